// Round 6
// baseline (220.483 us; speedup 1.0000x reference)
//
#include <hip/hip_runtime.h>

#define BATCH 4
#define CTX   2048
#define EMB   1024
#define HEAD  128

typedef __attribute__((ext_vector_type(8))) short bf16x8;
typedef __attribute__((ext_vector_type(4))) float f32x4;
typedef const __attribute__((address_space(1))) unsigned int* gas_t;
typedef __attribute__((address_space(3))) unsigned int* las_t;

#define FINF (__builtin_inff())
__device__ inline float fexp2(float x) { return __builtin_amdgcn_exp2f(x); }

// async global->LDS, 16B per lane. LDS dest = wave-uniform base + lane*16.
__device__ inline void cp16(const void* g, void* l) {
    __builtin_amdgcn_global_load_lds((gas_t)g, (las_t)l, 16, 0, 0);
}

__device__ inline unsigned short f2bf(float f) {
    union { float f; unsigned u; } v; v.f = f;
    unsigned r = v.u + 0x7fffu + ((v.u >> 16) & 1u);
    return (unsigned short)(r >> 16);
}
// HW packed f32x2 -> bf16x2, RNE (identical rounding to f2bf), 1 instr.
__device__ inline unsigned pk2(float a, float b) {
    unsigned r;
    asm("v_cvt_pk_bf16_f32 %0, %1, %2" : "=v"(r) : "v"(a), "v"(b));
    return r;
}
__device__ inline float bf2f(unsigned u16) {
    union { unsigned u; float f; } v; v.u = u16 << 16; return v.f;
}

// ---------------------------------------------------------------------------
// prep kernel (R5): one launch does
//   bx <  96 : W[1024][128] fp32 -> Wt[w][128][1024] bf16 (transpose)
//   bx >= 96 : x fp32 -> xb bf16 (8M elems over 512 blocks); block 96 also
//              zeroes the 128 per-(b,T) merge counters.
// grid 608 x 256.
// ---------------------------------------------------------------------------
__global__ __launch_bounds__(256)
void prep_kernel(const float* __restrict__ x,
                 const float* __restrict__ Wq, const float* __restrict__ Wk,
                 const float* __restrict__ Wv, unsigned short* __restrict__ Wt,
                 unsigned short* __restrict__ xb, int* __restrict__ cnt) {
    const int bx  = blockIdx.x;
    const int tid = threadIdx.x;
    if (bx < 96) {
        const int w  = bx >> 5;
        const int k0 = (bx & 15) * 64;
        const int h0 = ((bx >> 4) & 1) * 64;
        const float* W = (w == 0) ? Wq : (w == 1) ? Wk : Wv;
        __shared__ float Ts[64][65];
        #pragma unroll
        for (int it = 0; it < 4; ++it) {
            const int kk = (tid >> 4) + it * 16;
            const int c4 = (tid & 15) * 4;
            const float4 f = *(const float4*)&W[(size_t)(k0 + kk) * HEAD + h0 + c4];
            Ts[kk][c4 + 0] = f.x; Ts[kk][c4 + 1] = f.y;
            Ts[kk][c4 + 2] = f.z; Ts[kk][c4 + 3] = f.w;
        }
        __syncthreads();
        const int hr  = tid >> 2;
        const int kc0 = (tid & 3) * 16;
        union { unsigned u[8]; uint4 q[2]; } tmp;
        #pragma unroll
        for (int j = 0; j < 8; ++j)
            tmp.u[j] = pk2(Ts[kc0 + 2 * j][hr], Ts[kc0 + 2 * j + 1][hr]);
        unsigned short* dst = &Wt[(size_t)w * HEAD * EMB + (size_t)(h0 + hr) * EMB + k0 + kc0];
        ((uint4*)dst)[0] = tmp.q[0];
        ((uint4*)dst)[1] = tmp.q[1];
    } else {
        const int bi = bx - 96;            // 0..511
        if (bi == 0 && tid < BATCH * 32) cnt[tid] = 0;
        const size_t base = (size_t)bi * 16384;
        #pragma unroll
        for (int it = 0; it < 8; ++it) {
            const size_t idx = base + it * 2048 + tid * 8;
            const float4 a = *(const float4*)&x[idx];
            const float4 b = *(const float4*)&x[idx + 4];
            uint4 u;
            u.x = pk2(a.x, a.y); u.y = pk2(a.z, a.w);
            u.z = pk2(b.x, b.y); u.w = pk2(b.z, b.w);
            *(uint4*)&xb[idx] = u;
        }
    }
}

// ---------------------------------------------------------------------------
// QKV projection v6 (R5): consumes PRE-CONVERTED bf16 x (xb). A staged like B
// (bf16, 2 cp16/stage, plain ds_read_b128 fragments, zero conversion in the
// K-loop). Triple-buffered, distance-2, counted vmcnt(10). LDS 30KB.
// grid (256, 3), single-wave blocks, no barriers.
// ---------------------------------------------------------------------------
__global__ __launch_bounds__(64, 1)
void proj_kernel(const unsigned short* __restrict__ xb,
                 const unsigned short* __restrict__ Wt,
                 unsigned short* __restrict__ qb, unsigned short* __restrict__ kb,
                 unsigned short* __restrict__ vt) {
    __shared__ __align__(16) char smem[30720];
    char* Ab = smem;            // 3 x 2KB : x tile [32 tok][64B] bf16, swizzled
    char* Bb = smem + 6144;     // 3 x 8KB : W tile [128 h][64B] bf16, swizzled

    const int wsel = blockIdx.y;
    const int lane = threadIdx.x;
    const int p = lane >> 4, c = lane & 15;
    const int m0 = blockIdx.x * 32;
    const unsigned short* Wp = Wt + (size_t)wsel * HEAD * EMB;

    const int u2c = (c ^ (c >> 2)) & 3;    // row swizzle key (rows of 4x16B)

    auto stage = [&](int bi, int ks) {
        #pragma unroll
        for (int i = 0; i < 2; ++i) {      // A: 32 rows x 64B = 2KB
            const int f = i * 64 + lane;
            const int r = f >> 2, s = f & 3, q = s ^ ((r ^ (r >> 2)) & 3);
            cp16(&xb[(size_t)(m0 + r) * EMB + ks * 32 + q * 8],
                 Ab + bi * 2048 + i * 1024);
        }
        #pragma unroll
        for (int i = 0; i < 8; ++i) {      // B: 128 rows x 64B = 8KB
            const int f = i * 64 + lane;
            const int h = f >> 2, s = f & 3, q = s ^ ((h ^ (h >> 2)) & 3);
            cp16(&Wp[(size_t)h * EMB + ks * 32 + q * 8],
                 Bb + bi * 8192 + i * 1024);
        }
    };

    f32x4 acc[2][8];                       // [m-tile or n-tile][8 h-tiles]
    #pragma unroll
    for (int i = 0; i < 2; ++i)
        #pragma unroll
        for (int j = 0; j < 8; ++j) acc[i][j] = (f32x4){0.f, 0.f, 0.f, 0.f};

    stage(0, 0);
    stage(1, 1);
    int cur = 0, pre = 2;
    for (int ks = 0; ks < 32; ++ks) {
        // vmcnt(10): drain only the stage being consumed (10 loads/stage);
        // the in-flight next stage stays outstanding. Tail: vmcnt(0).
        if (ks == 31) __builtin_amdgcn_s_waitcnt(0x0F70);
        else          __builtin_amdgcn_s_waitcnt(0x0F7A);
        __builtin_amdgcn_sched_barrier(0x6);   // VALU/SALU may cross, mem may not
        const char* Ac = Ab + cur * 2048;
        const char* Bc = Bb + cur * 8192;
        bf16x8 xv[2], wf[8];
        #pragma unroll
        for (int mi = 0; mi < 2; ++mi)
            xv[mi] = *(const bf16x8*)(Ac + (mi * 16 + c) * 64 + ((p ^ u2c) * 16));
        #pragma unroll
        for (int nt = 0; nt < 8; ++nt)
            wf[nt] = *(const bf16x8*)(Bc + (nt * 16 + c) * 64 + ((p ^ u2c) * 16));
        if (ks + 2 < 32) stage(pre, ks + 2);   // distance-2 prefetch
        if (wsel < 2) {
            #pragma unroll
            for (int mi = 0; mi < 2; ++mi)
                #pragma unroll
                for (int nt = 0; nt < 8; ++nt)
                    acc[mi][nt] = __builtin_amdgcn_mfma_f32_16x16x32_bf16(xv[mi], wf[nt], acc[mi][nt], 0, 0, 0);
        } else {
            #pragma unroll
            for (int n2 = 0; n2 < 2; ++n2)
                #pragma unroll
                for (int mt = 0; mt < 8; ++mt)
                    acc[n2][mt] = __builtin_amdgcn_mfma_f32_16x16x32_bf16(wf[mt], xv[n2], acc[n2][mt], 0, 0, 0);
        }
        cur = (cur == 2) ? 0 : cur + 1;
        pre = (pre == 2) ? 0 : pre + 1;
    }

    if (wsel < 2) {
        // C[m = token = m0 + mi*16 + p*4 + rr][n = h = nt*16 + c]
        unsigned short* outp = (wsel == 0) ? qb : kb;
        #pragma unroll
        for (int mi = 0; mi < 2; ++mi)
            #pragma unroll
            for (int rr = 0; rr < 4; ++rr) {
                unsigned short* orow = outp + (size_t)(m0 + mi * 16 + p * 4 + rr) * HEAD + c;
                #pragma unroll
                for (int nt = 0; nt < 8; ++nt)
                    orow[nt * 16] = f2bf(acc[mi][nt][rr]);
            }
    } else {
        // C[m = h = mt*16 + p*4 + rr][n = token = m0 + n2*16 + c] -> vt[b][h][t]
        const int bidx = m0 >> 11;
        const int tl   = m0 & (CTX - 1);
        unsigned short* vbp = vt + (size_t)bidx * HEAD * CTX;
        #pragma unroll
        for (int mt = 0; mt < 8; ++mt)
            #pragma unroll
            for (int rr = 0; rr < 4; ++rr) {
                const int h = mt * 16 + p * 4 + rr;
                #pragma unroll
                for (int n2 = 0; n2 < 2; ++n2)
                    vbp[(size_t)h * CTX + tl + n2 * 16 + c] = f2bf(acc[n2][mt][rr]);
            }
    }
}

// ---------------------------------------------------------------------------
// Split-KV flash attention (R2 structure) + R5: LAST-BLOCK MERGE fusion.
// chunk = 256 kv, heavy-first, grid (144, 4). The last chunk-block to finish
// a (b,T) pair (device-scope atomic counter) merges all partials and writes
// the final fp32 output — no separate merge kernel.
// ---------------------------------------------------------------------------
__global__ __launch_bounds__(256, 2)
void attn_split_kernel(const unsigned short* __restrict__ qb,
                       const unsigned short* __restrict__ kb,
                       const unsigned short* __restrict__ vt,
                       unsigned short* __restrict__ pO,
                       float* __restrict__ pM, float* __restrict__ pL,
                       int* __restrict__ cnt, float* __restrict__ out) {
    __shared__ __align__(16) char smem[65536];
    char* Kb = smem;            // 2 x 16KB : [64 kv][128 h] bf16
    char* Vb = smem + 32768;    // 2 x 16KB : [128 h][64 kv] bf16

    const int b = blockIdx.y;
    // Heavy-first enumeration: T descending; nch(T) = T/4 + 1, sum = 144.
    int gi = blockIdx.x, T = 0, ch = 0;
    for (int t = 31; t >= 0; --t) {
        const int n = (t >> 2) + 1;
        if (gi < n) { T = t; ch = gi; break; }
        gi -= n;
    }
    const int nch    = (T >> 2) + 1;
    const int kstart = ch * 256;
    const int kend   = min(kstart + 256, 64 * (T + 1));
    const int nsteps = (kend - kstart) >> 6;
    const bool lastchunk = (ch == nch - 1);

    const int tid  = threadIdx.x;
    const int wv   = tid >> 6;
    const int lane = tid & 63;
    const int p = lane >> 4, c = lane & 15;
    const int t0 = T * 64;
    const int qg = t0 + wv * 16 + c;
    const int u7 = c & 7;

    const unsigned short* kbat = kb + (size_t)b * CTX * HEAD;
    const unsigned short* vbat = vt + (size_t)b * HEAD * CTX;

    bf16x8 qf[4];
    #pragma unroll
    for (int ks = 0; ks < 4; ++ks)
        qf[ks] = *(const bf16x8*)&qb[((size_t)b * CTX + t0 + wv * 16 + c) * HEAD + ks * 32 + p * 8];

    f32x4 o[8];
    #pragma unroll
    for (int i = 0; i < 8; ++i) o[i] = (f32x4){0.f, 0.f, 0.f, 0.f};
    float m = -FINF, l = 0.f;

    const int  slA = 32 * (p & 1) + c;
    const int  slB = slA + 16;
    const bool thi = (p >> 1) != 0;
    const float scale2 = 0.08838834764831845f * 1.44269504088896340f;  // 1/sqrt(128)*log2e

    auto stage = [&](int bi, int js) {
        const unsigned short* kg = kbat + (size_t)(kstart + js * 64) * HEAD;
        #pragma unroll
        for (int i = 0; i < 4; ++i) {      // K: 64 rows x 256B
            const int f = i * 256 + tid;
            const int r = f >> 4, s = f & 15, q = s ^ (r & 7);
            cp16(kg + (size_t)r * HEAD + q * 8, Kb + bi * 16384 + (f >> 6) * 1024);
        }
        const unsigned short* vg = vbat + kstart + js * 64;
        #pragma unroll
        for (int i = 0; i < 4; ++i) {      // V: 128 rows x 128B
            const int f = i * 256 + tid;
            const int r = f >> 3, s = f & 7, q = s ^ (r & 7);
            cp16(vg + (size_t)r * CTX + q * 8, Vb + bi * 16384 + (f >> 6) * 1024);
        }
    };

    stage(0, 0);
    for (int js = 0; js < nsteps; ++js) {
        const int cur = js & 1;
        __builtin_amdgcn_s_waitcnt(0);
        __syncthreads();                   // buf[cur] staged by all waves

        if (js + 1 < nsteps) stage(cur ^ 1, js + 1);   // issue ASAP after barrier

        bf16x8 kfr[4][4];
        #pragma unroll
        for (int nt = 0; nt < 4; ++nt) {
            const char* rp = Kb + cur * 16384 + (nt * 16 + c) * 256;
            #pragma unroll
            for (int ks = 0; ks < 4; ++ks)
                kfr[nt][ks] = *(const bf16x8*)(rp + (((ks * 4 + p) ^ u7) * 16));
        }

        f32x4 st[4];
        #pragma unroll
        for (int nt = 0; nt < 4; ++nt) st[nt] = (f32x4){0.f, 0.f, 0.f, 0.f};
        __builtin_amdgcn_s_setprio(1);
        #pragma unroll
        for (int ks = 0; ks < 4; ++ks)
            #pragma unroll
            for (int nt = 0; nt < 4; ++nt)
                st[nt] = __builtin_amdgcn_mfma_f32_16x16x32_bf16(kfr[nt][ks], qf[ks], st[nt], 0, 0, 0);
        __builtin_amdgcn_s_setprio(0);

        bf16x8 vfr[2][8];
        #pragma unroll
        for (int mt = 0; mt < 8; ++mt) {
            const char* rp = Vb + cur * 16384 + (mt * 16 + c) * 128;
            #pragma unroll
            for (int ch2 = 0; ch2 < 2; ++ch2)
                vfr[ch2][mt] = *(const bf16x8*)(rp + (((ch2 * 4 + p) ^ u7) * 16));
        }

        float s[4][4];
        float lm = -FINF;
        if (lastchunk && js == nsteps - 1) {
            #pragma unroll
            for (int nt = 0; nt < 4; ++nt)
                #pragma unroll
                for (int r = 0; r < 4; ++r) {
                    const int kv = kstart + js * 64 + nt * 16 + p * 4 + r;
                    float v = st[nt][r] * scale2;
                    v = (kv <= qg) ? v : -FINF;
                    s[nt][r] = v;
                    lm = fmaxf(lm, v);
                }
        } else {
            #pragma unroll
            for (int nt = 0; nt < 4; ++nt)
                #pragma unroll
                for (int r = 0; r < 4; ++r) {
                    const float v = st[nt][r] * scale2;
                    s[nt][r] = v;
                    lm = fmaxf(lm, v);
                }
        }
        lm = fmaxf(lm, __shfl_xor(lm, 16, 64));
        lm = fmaxf(lm, __shfl_xor(lm, 32, 64));
        const float m_new = fmaxf(m, lm);
        const float alpha = fexp2(m - m_new);
        float ls = 0.f;
        #pragma unroll
        for (int nt = 0; nt < 4; ++nt)
            #pragma unroll
            for (int r = 0; r < 4; ++r) {
                const float pv = fexp2(s[nt][r] - m_new);
                s[nt][r] = pv;
                ls += pv;
            }
        ls += __shfl_xor(ls, 16, 64);
        ls += __shfl_xor(ls, 32, 64);
        l = l * alpha + ls;
        m = m_new;
        #pragma unroll
        for (int i = 0; i < 8; ++i) {
            o[i][0] *= alpha; o[i][1] *= alpha;
            o[i][2] *= alpha; o[i][3] *= alpha;
        }
        #pragma unroll
        for (int ch2 = 0; ch2 < 2; ++ch2) {
            const unsigned pa0 = pk2(s[2*ch2][0],     s[2*ch2][1]);
            const unsigned pb0 = pk2(s[2*ch2][2],     s[2*ch2][3]);
            const unsigned pa1 = pk2(s[2*ch2 + 1][0], s[2*ch2 + 1][1]);
            const unsigned pb1 = pk2(s[2*ch2 + 1][2], s[2*ch2 + 1][3]);
            const unsigned u0a = __shfl((int)pa0, slA, 64), u0b = __shfl((int)pa1, slA, 64);
            const unsigned u1a = __shfl((int)pb0, slA, 64), u1b = __shfl((int)pb1, slA, 64);
            const unsigned u2a = __shfl((int)pa0, slB, 64), u2b = __shfl((int)pa1, slB, 64);
            const unsigned u3a = __shfl((int)pb0, slB, 64), u3b = __shfl((int)pb1, slB, 64);
            union { unsigned u[4]; bf16x8 v; } pf;
            pf.u[0] = thi ? u0b : u0a;
            pf.u[1] = thi ? u1b : u1a;
            pf.u[2] = thi ? u2b : u2a;
            pf.u[3] = thi ? u3b : u3a;
            __builtin_amdgcn_s_setprio(1);
            #pragma unroll
            for (int mt = 0; mt < 8; ++mt)
                o[mt] = __builtin_amdgcn_mfma_f32_16x16x32_bf16(vfr[ch2][mt], pf.v, o[mt], 0, 0, 0);
            __builtin_amdgcn_s_setprio(0);
        }
    }

    const size_t pbase = (size_t)(b * 32 + T) * 8 + ch;
    unsigned short* po = pO + pbase * (64 * 128) + (wv * 16 + c) * 128;
    #pragma unroll
    for (int mt = 0; mt < 8; ++mt) {
        uint2 u;
        u.x = pk2(o[mt][0], o[mt][1]);
        u.y = pk2(o[mt][2], o[mt][3]);
        *(uint2*)&po[mt * 16 + p * 4] = u;
    }
    if (p == 0) {
        pM[pbase * 64 + wv * 16 + c] = m;
        pL[pbase * 64 + wv * 16 + c] = l;
    }

    // ---- last-block merge (split-K pattern) ----
    __threadfence();                       // release this block's partials
    __syncthreads();
    int* lastp = (int*)smem;               // LDS buffers dead past here
    if (tid == 0) *lastp = atomicAdd(&cnt[b * 32 + T], 1);
    __syncthreads();
    if (*lastp != nch - 1) return;
    __threadfence();                       // acquire all other blocks' partials

    const int r  = tid >> 2;
    const int c0 = (tid & 3) * 32;
    const size_t base = (size_t)(b * 32 + T) * 8;
    float mv[8], lv[8];
    float M = -FINF;
    #pragma unroll
    for (int i = 0; i < 8; ++i) {
        if (i < nch) { mv[i] = pM[(base + i) * 64 + r]; lv[i] = pL[(base + i) * 64 + r]; }
        else         { mv[i] = -FINF;                   lv[i] = 0.f; }
        M = fmaxf(M, mv[i]);
    }
    float w[8], L = 0.f;
    #pragma unroll
    for (int i = 0; i < 8; ++i) { w[i] = fexp2(mv[i] - M); L += w[i] * lv[i]; }
    const float inv = 1.f / L;

    float acc[32];
    #pragma unroll
    for (int j = 0; j < 32; ++j) acc[j] = 0.f;
    #pragma unroll
    for (int i = 0; i < 8; ++i) {
        if (i < nch) {
            const unsigned* s32 = (const unsigned*)(pO + (base + i) * (64 * 128) + r * 128 + c0);
            const float wi = w[i];
            #pragma unroll
            for (int jw = 0; jw < 16; ++jw) {
                const unsigned u = s32[jw];
                acc[2 * jw]     += wi * bf2f(u & 0xffffu);
                acc[2 * jw + 1] += wi * bf2f(u >> 16);
            }
        }
    }
    float* orow = out + ((size_t)b * CTX + T * 64 + r) * HEAD + c0;
    #pragma unroll
    for (int j4 = 0; j4 < 8; ++j4) {
        float4 ov = make_float4(acc[4*j4] * inv, acc[4*j4+1] * inv,
                                acc[4*j4+2] * inv, acc[4*j4+3] * inv);
        *(float4*)&orow[4 * j4] = ov;
    }
}

// ---------------------------------------------------------------------------
// Fallback attention: single-wave blocks, used if ws too small for split.
// ---------------------------------------------------------------------------
__global__ __launch_bounds__(64, 1)
void attn_kernel(const unsigned short* __restrict__ qb,
                 const unsigned short* __restrict__ kb,
                 const unsigned short* __restrict__ vt,
                 float* __restrict__ out) {
    __shared__ __align__(16) char smem[65536];
    char* Kb = smem;
    char* Vb = smem + 32768;
    const int bx   = blockIdx.x;
    const int b    = bx & 3;
    const int tile = 127 - (bx >> 2);
    const int lane = threadIdx.x;
    const int p = lane >> 4, c = lane & 15;
    const int t0 = tile * 16;
    const int qg = t0 + c;
    const int u7 = c & 7;
    const unsigned short* kbat = kb + (size_t)b * CTX * HEAD;
    const unsigned short* vbat = vt + (size_t)b * HEAD * CTX;
    bf16x8 qf[4];
    #pragma unroll
    for (int ks = 0; ks < 4; ++ks)
        qf[ks] = *(const bf16x8*)&qb[((size_t)b * CTX + t0 + c) * HEAD + ks * 32 + p * 8];
    f32x4 o[8];
    #pragma unroll
    for (int i = 0; i < 8; ++i) o[i] = (f32x4){0.f, 0.f, 0.f, 0.f};
    float m = -FINF, l = 0.f;
    const int  slA = 32 * (p & 1) + c;
    const int  slB = slA + 16;
    const bool thi = (p >> 1) != 0;
    const int  nsteps = (tile + 4) >> 2;
    const float scale2 = 0.08838834764831845f * 1.44269504088896340f;
    auto stage = [&](int bi, int js) {
        const unsigned short* kg = kbat + (size_t)(js * 64) * HEAD;
        #pragma unroll
        for (int i = 0; i < 16; ++i) {
            const int f = i * 64 + lane;
            const int r = f >> 4, s = f & 15, q = s ^ (r & 7);
            cp16(kg + (size_t)r * HEAD + q * 8, Kb + bi * 16384 + i * 1024);
        }
        #pragma unroll
        for (int i = 0; i < 16; ++i) {
            const int f = i * 64 + lane;
            const int r = f >> 3, s = f & 7, q = s ^ (r & 7);
            cp16(vbat + (size_t)r * CTX + js * 64 + q * 8, Vb + bi * 16384 + i * 1024);
        }
    };
    stage(0, 0);
    for (int js = 0; js < nsteps; ++js) {
        const int cur = js & 1;
        __builtin_amdgcn_s_waitcnt(0);
        bf16x8 kfr[4][4], vfr[2][8];
        #pragma unroll
        for (int nt = 0; nt < 4; ++nt) {
            const char* rp = Kb + cur * 16384 + (nt * 16 + c) * 256;
            #pragma unroll
            for (int ks = 0; ks < 4; ++ks)
                kfr[nt][ks] = *(const bf16x8*)(rp + (((ks * 4 + p) ^ u7) * 16));
        }
        #pragma unroll
        for (int mt = 0; mt < 8; ++mt) {
            const char* rp = Vb + cur * 16384 + (mt * 16 + c) * 128;
            #pragma unroll
            for (int ch = 0; ch < 2; ++ch)
                vfr[ch][mt] = *(const bf16x8*)(rp + (((ch * 4 + p) ^ u7) * 16));
        }
        if (js + 1 < nsteps) stage(cur ^ 1, js + 1);
        const int c0 = js * 64;
        f32x4 st[4];
        #pragma unroll
        for (int nt = 0; nt < 4; ++nt) st[nt] = (f32x4){0.f, 0.f, 0.f, 0.f};
        #pragma unroll
        for (int ks = 0; ks < 4; ++ks)
            #pragma unroll
            for (int nt = 0; nt < 4; ++nt)
                st[nt] = __builtin_amdgcn_mfma_f32_16x16x32_bf16(kfr[nt][ks], qf[ks], st[nt], 0, 0, 0);
        float s[4][4];
        float lm = -FINF;
        if (js == nsteps - 1) {
            #pragma unroll
            for (int nt = 0; nt < 4; ++nt)
                #pragma unroll
                for (int r = 0; r < 4; ++r) {
                    const int kv = c0 + nt * 16 + p * 4 + r;
                    float v = st[nt][r] * scale2;
                    v = (kv <= qg) ? v : -FINF;
                    s[nt][r] = v;
                    lm = fmaxf(lm, v);
                }
        } else {
            #pragma unroll
            for (int nt = 0; nt < 4; ++nt)
                #pragma unroll
                for (int r = 0; r < 4; ++r) {
                    const float v = st[nt][r] * scale2;
                    s[nt][r] = v;
                    lm = fmaxf(lm, v);
                }
        }
        lm = fmaxf(lm, __shfl_xor(lm, 16, 64));
        lm = fmaxf(lm, __shfl_xor(lm, 32, 64));
        const float m_new = fmaxf(m, lm);
        const float alpha = fexp2(m - m_new);
        float ls = 0.f;
        #pragma unroll
        for (int nt = 0; nt < 4; ++nt)
            #pragma unroll
            for (int r = 0; r < 4; ++r) {
                const float pv = fexp2(s[nt][r] - m_new);
                s[nt][r] = pv;
                ls += pv;
            }
        ls += __shfl_xor(ls, 16, 64);
        ls += __shfl_xor(ls, 32, 64);
        l = l * alpha + ls;
        m = m_new;
        #pragma unroll
        for (int i = 0; i < 8; ++i) {
            o[i][0] *= alpha; o[i][1] *= alpha;
            o[i][2] *= alpha; o[i][3] *= alpha;
        }
        #pragma unroll
        for (int ch = 0; ch < 2; ++ch) {
            const unsigned pa0 = pk2(s[2*ch][0],     s[2*ch][1]);
            const unsigned pb0 = pk2(s[2*ch][2],     s[2*ch][3]);
            const unsigned pa1 = pk2(s[2*ch + 1][0], s[2*ch + 1][1]);
            const unsigned pb1 = pk2(s[2*ch + 1][2], s[2*ch + 1][3]);
            const unsigned u0a = __shfl((int)pa0, slA, 64), u0b = __shfl((int)pa1, slA, 64);
            const unsigned u1a = __shfl((int)pb0, slA, 64), u1b = __shfl((int)pb1, slA, 64);
            const unsigned u2a = __shfl((int)pa0, slB, 64), u2b = __shfl((int)pa1, slB, 64);
            const unsigned u3a = __shfl((int)pb0, slB, 64), u3b = __shfl((int)pb1, slB, 64);
            union { unsigned u[4]; bf16x8 v; } pf;
            pf.u[0] = thi ? u0b : u0a;
            pf.u[1] = thi ? u1b : u1a;
            pf.u[2] = thi ? u2b : u2a;
            pf.u[3] = thi ? u3b : u3a;
            #pragma unroll
            for (int mt = 0; mt < 8; ++mt)
                o[mt] = __builtin_amdgcn_mfma_f32_16x16x32_bf16(vfr[ch][mt], pf.v, o[mt], 0, 0, 0);
        }
    }
    const float linv = 1.f / l;
    float* orow = out + ((size_t)b * CTX + t0 + c) * HEAD;
    #pragma unroll
    for (int mt = 0; mt < 8; ++mt) {
        float4 ov = make_float4(o[mt][0] * linv, o[mt][1] * linv,
                                o[mt][2] * linv, o[mt][3] * linv);
        *(float4*)&orow[mt * 16 + p * 4] = ov;
    }
}

// ---------------------------------------------------------------------------
extern "C" void kernel_launch(void* const* d_in, const int* in_sizes, int n_in,
                              void* d_out, int out_size, void* d_ws, size_t ws_size,
                              hipStream_t stream) {
    const float* x  = (const float*)d_in[0];
    const float* Wq = (const float*)d_in[1];
    const float* Wk = (const float*)d_in[2];
    const float* Wv = (const float*)d_in[3];
    float* out = (float*)d_out;

    unsigned short* Wt = (unsigned short*)d_ws;                 // 3*128*1024
    unsigned short* xb = Wt + (size_t)3 * HEAD * EMB;           // 8192*1024 bf16
    unsigned short* qb = xb + (size_t)BATCH * CTX * EMB;
    unsigned short* kb = qb + (size_t)BATCH * CTX * HEAD;
    unsigned short* vt = kb + (size_t)BATCH * CTX * HEAD;
    unsigned short* pO = vt + (size_t)BATCH * CTX * HEAD;       // 4*32*8*64*128 bf16
    float* pM = (float*)(pO + (size_t)BATCH * 32 * 8 * 64 * 128);
    float* pL = pM + (size_t)BATCH * 32 * 8 * 64;
    int*   cnt = (int*)(pL + (size_t)BATCH * 32 * 8 * 64);

    const size_t need = (size_t)((char*)(cnt + BATCH * 32) - (char*)d_ws);

    prep_kernel<<<608, 256, 0, stream>>>(x, Wq, Wk, Wv, Wt, xb, cnt);
    proj_kernel<<<dim3((BATCH * CTX) / 32, 3), 64, 0, stream>>>(xb, Wt, qb, kb, vt);
    if (ws_size >= need) {
        attn_split_kernel<<<dim3(144, 4), 256, 0, stream>>>(qb, kb, vt, pO, pM, pL, cnt, out);
    } else {
        attn_kernel<<<BATCH * (CTX / 16), 64, 0, stream>>>(qb, kb, vt, out);
    }
}

// Round 7
// 123.355 us; speedup vs baseline: 1.7874x; 1.7874x over previous
//
#include <hip/hip_runtime.h>

#define BATCH 4
#define CTX   2048
#define EMB   1024
#define HEAD  128

typedef __attribute__((ext_vector_type(8))) short bf16x8;
typedef __attribute__((ext_vector_type(4))) float f32x4;
typedef const __attribute__((address_space(1))) unsigned int* gas_t;
typedef __attribute__((address_space(3))) unsigned int* las_t;

#define FINF (__builtin_inff())
__device__ inline float fexp2(float x) { return __builtin_amdgcn_exp2f(x); }

// async global->LDS, 16B per lane. LDS dest = wave-uniform base + lane*16.
__device__ inline void cp16(const void* g, void* l) {
    __builtin_amdgcn_global_load_lds((gas_t)g, (las_t)l, 16, 0, 0);
}

__device__ inline unsigned short f2bf(float f) {
    union { float f; unsigned u; } v; v.f = f;
    unsigned r = v.u + 0x7fffu + ((v.u >> 16) & 1u);
    return (unsigned short)(r >> 16);
}
// HW packed f32x2 -> bf16x2, RNE (identical rounding to f2bf), 1 instr.
__device__ inline unsigned pk2(float a, float b) {
    unsigned r;
    asm("v_cvt_pk_bf16_f32 %0, %1, %2" : "=v"(r) : "v"(a), "v"(b));
    return r;
}
__device__ inline float bf2f(unsigned u16) {
    union { unsigned u; float f; } v; v.u = u16 << 16; return v.f;
}

// ---------------------------------------------------------------------------
// prep kernel (R5, kept): one launch does
//   bx <  96 : W[1024][128] fp32 -> Wt[w][128][1024] bf16 (transpose)
//   bx >= 96 : x fp32 -> xb bf16 (8M elems over 512 blocks)
// grid 608 x 256.
// ---------------------------------------------------------------------------
__global__ __launch_bounds__(256)
void prep_kernel(const float* __restrict__ x,
                 const float* __restrict__ Wq, const float* __restrict__ Wk,
                 const float* __restrict__ Wv, unsigned short* __restrict__ Wt,
                 unsigned short* __restrict__ xb) {
    const int bx  = blockIdx.x;
    const int tid = threadIdx.x;
    if (bx < 96) {
        const int w  = bx >> 5;
        const int k0 = (bx & 15) * 64;
        const int h0 = ((bx >> 4) & 1) * 64;
        const float* W = (w == 0) ? Wq : (w == 1) ? Wk : Wv;
        __shared__ float Ts[64][65];
        #pragma unroll
        for (int it = 0; it < 4; ++it) {
            const int kk = (tid >> 4) + it * 16;
            const int c4 = (tid & 15) * 4;
            const float4 f = *(const float4*)&W[(size_t)(k0 + kk) * HEAD + h0 + c4];
            Ts[kk][c4 + 0] = f.x; Ts[kk][c4 + 1] = f.y;
            Ts[kk][c4 + 2] = f.z; Ts[kk][c4 + 3] = f.w;
        }
        __syncthreads();
        const int hr  = tid >> 2;
        const int kc0 = (tid & 3) * 16;
        union { unsigned u[8]; uint4 q[2]; } tmp;
        #pragma unroll
        for (int j = 0; j < 8; ++j)
            tmp.u[j] = pk2(Ts[kc0 + 2 * j][hr], Ts[kc0 + 2 * j + 1][hr]);
        unsigned short* dst = &Wt[(size_t)w * HEAD * EMB + (size_t)(h0 + hr) * EMB + k0 + kc0];
        ((uint4*)dst)[0] = tmp.q[0];
        ((uint4*)dst)[1] = tmp.q[1];
    } else {
        const int bi = bx - 96;            // 0..511
        const size_t base = (size_t)bi * 16384;
        #pragma unroll
        for (int it = 0; it < 8; ++it) {
            const size_t idx = base + it * 2048 + tid * 8;
            const float4 a = *(const float4*)&x[idx];
            const float4 b = *(const float4*)&x[idx + 4];
            uint4 u;
            u.x = pk2(a.x, a.y); u.y = pk2(a.z, a.w);
            u.z = pk2(b.x, b.y); u.w = pk2(b.z, b.w);
            *(uint4*)&xb[idx] = u;
        }
    }
}

// ---------------------------------------------------------------------------
// QKV projection v6 (R5, kept): consumes PRE-CONVERTED bf16 x (xb). A staged
// like B (bf16, 2 cp16/stage, plain ds_read_b128 fragments, zero conversion
// in the K-loop). Triple-buffered, distance-2, counted vmcnt(10). LDS 30KB.
// grid (256, 3), single-wave blocks, no barriers.
// ---------------------------------------------------------------------------
__global__ __launch_bounds__(64, 1)
void proj_kernel(const unsigned short* __restrict__ xb,
                 const unsigned short* __restrict__ Wt,
                 unsigned short* __restrict__ qb, unsigned short* __restrict__ kb,
                 unsigned short* __restrict__ vt) {
    __shared__ __align__(16) char smem[30720];
    char* Ab = smem;            // 3 x 2KB : x tile [32 tok][64B] bf16, swizzled
    char* Bb = smem + 6144;     // 3 x 8KB : W tile [128 h][64B] bf16, swizzled

    const int wsel = blockIdx.y;
    const int lane = threadIdx.x;
    const int p = lane >> 4, c = lane & 15;
    const int m0 = blockIdx.x * 32;
    const unsigned short* Wp = Wt + (size_t)wsel * HEAD * EMB;

    const int u2c = (c ^ (c >> 2)) & 3;    // row swizzle key (rows of 4x16B)

    auto stage = [&](int bi, int ks) {
        #pragma unroll
        for (int i = 0; i < 2; ++i) {      // A: 32 rows x 64B = 2KB
            const int f = i * 64 + lane;
            const int r = f >> 2, s = f & 3, q = s ^ ((r ^ (r >> 2)) & 3);
            cp16(&xb[(size_t)(m0 + r) * EMB + ks * 32 + q * 8],
                 Ab + bi * 2048 + i * 1024);
        }
        #pragma unroll
        for (int i = 0; i < 8; ++i) {      // B: 128 rows x 64B = 8KB
            const int f = i * 64 + lane;
            const int h = f >> 2, s = f & 3, q = s ^ ((h ^ (h >> 2)) & 3);
            cp16(&Wp[(size_t)h * EMB + ks * 32 + q * 8],
                 Bb + bi * 8192 + i * 1024);
        }
    };

    f32x4 acc[2][8];                       // [m-tile or n-tile][8 h-tiles]
    #pragma unroll
    for (int i = 0; i < 2; ++i)
        #pragma unroll
        for (int j = 0; j < 8; ++j) acc[i][j] = (f32x4){0.f, 0.f, 0.f, 0.f};

    stage(0, 0);
    stage(1, 1);
    int cur = 0, pre = 2;
    for (int ks = 0; ks < 32; ++ks) {
        // vmcnt(10): drain only the stage being consumed (10 loads/stage);
        // the in-flight next stage stays outstanding. Tail: vmcnt(0).
        if (ks == 31) __builtin_amdgcn_s_waitcnt(0x0F70);
        else          __builtin_amdgcn_s_waitcnt(0x0F7A);
        __builtin_amdgcn_sched_barrier(0x6);   // VALU/SALU may cross, mem may not
        const char* Ac = Ab + cur * 2048;
        const char* Bc = Bb + cur * 8192;
        bf16x8 xv[2], wf[8];
        #pragma unroll
        for (int mi = 0; mi < 2; ++mi)
            xv[mi] = *(const bf16x8*)(Ac + (mi * 16 + c) * 64 + ((p ^ u2c) * 16));
        #pragma unroll
        for (int nt = 0; nt < 8; ++nt)
            wf[nt] = *(const bf16x8*)(Bc + (nt * 16 + c) * 64 + ((p ^ u2c) * 16));
        if (ks + 2 < 32) stage(pre, ks + 2);   // distance-2 prefetch
        if (wsel < 2) {
            #pragma unroll
            for (int mi = 0; mi < 2; ++mi)
                #pragma unroll
                for (int nt = 0; nt < 8; ++nt)
                    acc[mi][nt] = __builtin_amdgcn_mfma_f32_16x16x32_bf16(xv[mi], wf[nt], acc[mi][nt], 0, 0, 0);
        } else {
            #pragma unroll
            for (int n2 = 0; n2 < 2; ++n2)
                #pragma unroll
                for (int mt = 0; mt < 8; ++mt)
                    acc[n2][mt] = __builtin_amdgcn_mfma_f32_16x16x32_bf16(wf[mt], xv[n2], acc[n2][mt], 0, 0, 0);
        }
        cur = (cur == 2) ? 0 : cur + 1;
        pre = (pre == 2) ? 0 : pre + 1;
    }

    if (wsel < 2) {
        // C[m = token = m0 + mi*16 + p*4 + rr][n = h = nt*16 + c]
        unsigned short* outp = (wsel == 0) ? qb : kb;
        #pragma unroll
        for (int mi = 0; mi < 2; ++mi)
            #pragma unroll
            for (int rr = 0; rr < 4; ++rr) {
                unsigned short* orow = outp + (size_t)(m0 + mi * 16 + p * 4 + rr) * HEAD + c;
                #pragma unroll
                for (int nt = 0; nt < 8; ++nt)
                    orow[nt * 16] = f2bf(acc[mi][nt][rr]);
            }
    } else {
        // C[m = h = mt*16 + p*4 + rr][n = token = m0 + n2*16 + c] -> vt[b][h][t]
        const int bidx = m0 >> 11;
        const int tl   = m0 & (CTX - 1);
        unsigned short* vbp = vt + (size_t)bidx * HEAD * CTX;
        #pragma unroll
        for (int mt = 0; mt < 8; ++mt)
            #pragma unroll
            for (int rr = 0; rr < 4; ++rr) {
                const int h = mt * 16 + p * 4 + rr;
                #pragma unroll
                for (int n2 = 0; n2 < 2; ++n2)
                    vbp[(size_t)h * CTX + tl + n2 * 16 + c] = f2bf(acc[n2][mt][rr]);
            }
    }
}

// ---------------------------------------------------------------------------
// Split-KV flash attention (R2 structure, R6: fence-fusion REVERTED —
// device-scope __threadfence on gfx950 = cross-XCD L2 writeback, 576 blocks
// serialized on it = +120us. Separate merge kernel is far cheaper.)
// chunk = 256 kv, heavy-first, grid (144, 4).
// ---------------------------------------------------------------------------
__global__ __launch_bounds__(256, 2)
void attn_split_kernel(const unsigned short* __restrict__ qb,
                       const unsigned short* __restrict__ kb,
                       const unsigned short* __restrict__ vt,
                       unsigned short* __restrict__ pO,
                       float* __restrict__ pM, float* __restrict__ pL) {
    __shared__ __align__(16) char smem[65536];
    char* Kb = smem;            // 2 x 16KB : [64 kv][128 h] bf16
    char* Vb = smem + 32768;    // 2 x 16KB : [128 h][64 kv] bf16

    const int b = blockIdx.y;
    // Heavy-first enumeration: T descending; nch(T) = T/4 + 1, sum = 144.
    int gi = blockIdx.x, T = 0, ch = 0;
    for (int t = 31; t >= 0; --t) {
        const int n = (t >> 2) + 1;
        if (gi < n) { T = t; ch = gi; break; }
        gi -= n;
    }
    const int nch    = (T >> 2) + 1;
    const int kstart = ch * 256;
    const int kend   = min(kstart + 256, 64 * (T + 1));
    const int nsteps = (kend - kstart) >> 6;
    const bool lastchunk = (ch == nch - 1);

    const int tid  = threadIdx.x;
    const int wv   = tid >> 6;
    const int lane = tid & 63;
    const int p = lane >> 4, c = lane & 15;
    const int t0 = T * 64;
    const int qg = t0 + wv * 16 + c;
    const int u7 = c & 7;

    const unsigned short* kbat = kb + (size_t)b * CTX * HEAD;
    const unsigned short* vbat = vt + (size_t)b * HEAD * CTX;

    bf16x8 qf[4];
    #pragma unroll
    for (int ks = 0; ks < 4; ++ks)
        qf[ks] = *(const bf16x8*)&qb[((size_t)b * CTX + t0 + wv * 16 + c) * HEAD + ks * 32 + p * 8];

    f32x4 o[8];
    #pragma unroll
    for (int i = 0; i < 8; ++i) o[i] = (f32x4){0.f, 0.f, 0.f, 0.f};
    float m = -FINF, l = 0.f;

    const int  slA = 32 * (p & 1) + c;
    const int  slB = slA + 16;
    const bool thi = (p >> 1) != 0;
    const float scale2 = 0.08838834764831845f * 1.44269504088896340f;  // 1/sqrt(128)*log2e

    auto stage = [&](int bi, int js) {
        const unsigned short* kg = kbat + (size_t)(kstart + js * 64) * HEAD;
        #pragma unroll
        for (int i = 0; i < 4; ++i) {      // K: 64 rows x 256B
            const int f = i * 256 + tid;
            const int r = f >> 4, s = f & 15, q = s ^ (r & 7);
            cp16(kg + (size_t)r * HEAD + q * 8, Kb + bi * 16384 + (f >> 6) * 1024);
        }
        const unsigned short* vg = vbat + kstart + js * 64;
        #pragma unroll
        for (int i = 0; i < 4; ++i) {      // V: 128 rows x 128B
            const int f = i * 256 + tid;
            const int r = f >> 3, s = f & 7, q = s ^ (r & 7);
            cp16(vg + (size_t)r * CTX + q * 8, Vb + bi * 16384 + (f >> 6) * 1024);
        }
    };

    stage(0, 0);
    for (int js = 0; js < nsteps; ++js) {
        const int cur = js & 1;
        __builtin_amdgcn_s_waitcnt(0);
        __syncthreads();                   // buf[cur] staged by all waves

        if (js + 1 < nsteps) stage(cur ^ 1, js + 1);   // issue ASAP after barrier

        bf16x8 kfr[4][4];
        #pragma unroll
        for (int nt = 0; nt < 4; ++nt) {
            const char* rp = Kb + cur * 16384 + (nt * 16 + c) * 256;
            #pragma unroll
            for (int ks = 0; ks < 4; ++ks)
                kfr[nt][ks] = *(const bf16x8*)(rp + (((ks * 4 + p) ^ u7) * 16));
        }

        f32x4 st[4];
        #pragma unroll
        for (int nt = 0; nt < 4; ++nt) st[nt] = (f32x4){0.f, 0.f, 0.f, 0.f};
        __builtin_amdgcn_s_setprio(1);
        #pragma unroll
        for (int ks = 0; ks < 4; ++ks)
            #pragma unroll
            for (int nt = 0; nt < 4; ++nt)
                st[nt] = __builtin_amdgcn_mfma_f32_16x16x32_bf16(kfr[nt][ks], qf[ks], st[nt], 0, 0, 0);
        __builtin_amdgcn_s_setprio(0);

        bf16x8 vfr[2][8];
        #pragma unroll
        for (int mt = 0; mt < 8; ++mt) {
            const char* rp = Vb + cur * 16384 + (mt * 16 + c) * 128;
            #pragma unroll
            for (int ch2 = 0; ch2 < 2; ++ch2)
                vfr[ch2][mt] = *(const bf16x8*)(rp + (((ch2 * 4 + p) ^ u7) * 16));
        }

        float s[4][4];
        float lm = -FINF;
        if (lastchunk && js == nsteps - 1) {
            #pragma unroll
            for (int nt = 0; nt < 4; ++nt)
                #pragma unroll
                for (int r = 0; r < 4; ++r) {
                    const int kv = kstart + js * 64 + nt * 16 + p * 4 + r;
                    float v = st[nt][r] * scale2;
                    v = (kv <= qg) ? v : -FINF;
                    s[nt][r] = v;
                    lm = fmaxf(lm, v);
                }
        } else {
            #pragma unroll
            for (int nt = 0; nt < 4; ++nt)
                #pragma unroll
                for (int r = 0; r < 4; ++r) {
                    const float v = st[nt][r] * scale2;
                    s[nt][r] = v;
                    lm = fmaxf(lm, v);
                }
        }
        lm = fmaxf(lm, __shfl_xor(lm, 16, 64));
        lm = fmaxf(lm, __shfl_xor(lm, 32, 64));
        const float m_new = fmaxf(m, lm);
        const float alpha = fexp2(m - m_new);
        float ls = 0.f;
        #pragma unroll
        for (int nt = 0; nt < 4; ++nt)
            #pragma unroll
            for (int r = 0; r < 4; ++r) {
                const float pv = fexp2(s[nt][r] - m_new);
                s[nt][r] = pv;
                ls += pv;
            }
        ls += __shfl_xor(ls, 16, 64);
        ls += __shfl_xor(ls, 32, 64);
        l = l * alpha + ls;
        m = m_new;
        #pragma unroll
        for (int i = 0; i < 8; ++i) {
            o[i][0] *= alpha; o[i][1] *= alpha;
            o[i][2] *= alpha; o[i][3] *= alpha;
        }
        #pragma unroll
        for (int ch2 = 0; ch2 < 2; ++ch2) {
            const unsigned pa0 = pk2(s[2*ch2][0],     s[2*ch2][1]);
            const unsigned pb0 = pk2(s[2*ch2][2],     s[2*ch2][3]);
            const unsigned pa1 = pk2(s[2*ch2 + 1][0], s[2*ch2 + 1][1]);
            const unsigned pb1 = pk2(s[2*ch2 + 1][2], s[2*ch2 + 1][3]);
            const unsigned u0a = __shfl((int)pa0, slA, 64), u0b = __shfl((int)pa1, slA, 64);
            const unsigned u1a = __shfl((int)pb0, slA, 64), u1b = __shfl((int)pb1, slA, 64);
            const unsigned u2a = __shfl((int)pa0, slB, 64), u2b = __shfl((int)pa1, slB, 64);
            const unsigned u3a = __shfl((int)pb0, slB, 64), u3b = __shfl((int)pb1, slB, 64);
            union { unsigned u[4]; bf16x8 v; } pf;
            pf.u[0] = thi ? u0b : u0a;
            pf.u[1] = thi ? u1b : u1a;
            pf.u[2] = thi ? u2b : u2a;
            pf.u[3] = thi ? u3b : u3a;
            __builtin_amdgcn_s_setprio(1);
            #pragma unroll
            for (int mt = 0; mt < 8; ++mt)
                o[mt] = __builtin_amdgcn_mfma_f32_16x16x32_bf16(vfr[ch2][mt], pf.v, o[mt], 0, 0, 0);
            __builtin_amdgcn_s_setprio(0);
        }
    }

    const size_t pbase = (size_t)(b * 32 + T) * 8 + ch;
    unsigned short* po = pO + pbase * (64 * 128) + (wv * 16 + c) * 128;
    #pragma unroll
    for (int mt = 0; mt < 8; ++mt) {
        uint2 u;
        u.x = pk2(o[mt][0], o[mt][1]);
        u.y = pk2(o[mt][2], o[mt][3]);
        *(uint2*)&po[mt * 16 + p * 4] = u;
    }
    if (p == 0) {
        pM[pbase * 64 + wv * 16 + c] = m;
        pL[pbase * 64 + wv * 16 + c] = l;
    }
}

// ---------------------------------------------------------------------------
// Merge up to 8 partial chunks. grid (32, 4), 256 threads.
// ---------------------------------------------------------------------------
__global__ __launch_bounds__(256)
void attn_merge_kernel(const unsigned short* __restrict__ pO,
                       const float* __restrict__ pM, const float* __restrict__ pL,
                       float* __restrict__ out) {
    const int T = blockIdx.x, b = blockIdx.y;
    const int nch = (T >> 2) + 1;
    const int tid = threadIdx.x;
    const int r   = tid >> 2;
    const int c0  = (tid & 3) * 32;
    const size_t base = (size_t)(b * 32 + T) * 8;

    float mv[8], lv[8];
    float M = -FINF;
    #pragma unroll
    for (int i = 0; i < 8; ++i) {
        if (i < nch) { mv[i] = pM[(base + i) * 64 + r]; lv[i] = pL[(base + i) * 64 + r]; }
        else         { mv[i] = -FINF;                   lv[i] = 0.f; }
        M = fmaxf(M, mv[i]);
    }
    float w[8], L = 0.f;
    #pragma unroll
    for (int i = 0; i < 8; ++i) { w[i] = fexp2(mv[i] - M); L += w[i] * lv[i]; }
    const float inv = 1.f / L;

    float acc[32];
    #pragma unroll
    for (int j = 0; j < 32; ++j) acc[j] = 0.f;
    #pragma unroll
    for (int i = 0; i < 8; ++i) {
        if (i < nch) {
            const unsigned* s32 = (const unsigned*)(pO + (base + i) * (64 * 128) + r * 128 + c0);
            const float wi = w[i];
            #pragma unroll
            for (int jw = 0; jw < 16; ++jw) {
                const unsigned u = s32[jw];
                acc[2 * jw]     += wi * bf2f(u & 0xffffu);
                acc[2 * jw + 1] += wi * bf2f(u >> 16);
            }
        }
    }
    float* orow = out + ((size_t)b * CTX + T * 64 + r) * HEAD + c0;
    #pragma unroll
    for (int j4 = 0; j4 < 8; ++j4) {
        float4 ov = make_float4(acc[4*j4] * inv, acc[4*j4+1] * inv,
                                acc[4*j4+2] * inv, acc[4*j4+3] * inv);
        *(float4*)&orow[4 * j4] = ov;
    }
}

// ---------------------------------------------------------------------------
// Fallback attention: single-wave blocks, used if ws too small for split.
// ---------------------------------------------------------------------------
__global__ __launch_bounds__(64, 1)
void attn_kernel(const unsigned short* __restrict__ qb,
                 const unsigned short* __restrict__ kb,
                 const unsigned short* __restrict__ vt,
                 float* __restrict__ out) {
    __shared__ __align__(16) char smem[65536];
    char* Kb = smem;
    char* Vb = smem + 32768;
    const int bx   = blockIdx.x;
    const int b    = bx & 3;
    const int tile = 127 - (bx >> 2);
    const int lane = threadIdx.x;
    const int p = lane >> 4, c = lane & 15;
    const int t0 = tile * 16;
    const int qg = t0 + c;
    const int u7 = c & 7;
    const unsigned short* kbat = kb + (size_t)b * CTX * HEAD;
    const unsigned short* vbat = vt + (size_t)b * HEAD * CTX;
    bf16x8 qf[4];
    #pragma unroll
    for (int ks = 0; ks < 4; ++ks)
        qf[ks] = *(const bf16x8*)&qb[((size_t)b * CTX + t0 + c) * HEAD + ks * 32 + p * 8];
    f32x4 o[8];
    #pragma unroll
    for (int i = 0; i < 8; ++i) o[i] = (f32x4){0.f, 0.f, 0.f, 0.f};
    float m = -FINF, l = 0.f;
    const int  slA = 32 * (p & 1) + c;
    const int  slB = slA + 16;
    const bool thi = (p >> 1) != 0;
    const int  nsteps = (tile + 4) >> 2;
    const float scale2 = 0.08838834764831845f * 1.44269504088896340f;
    auto stage = [&](int bi, int js) {
        const unsigned short* kg = kbat + (size_t)(js * 64) * HEAD;
        #pragma unroll
        for (int i = 0; i < 16; ++i) {
            const int f = i * 64 + lane;
            const int r = f >> 4, s = f & 15, q = s ^ (r & 7);
            cp16(kg + (size_t)r * HEAD + q * 8, Kb + bi * 16384 + i * 1024);
        }
        #pragma unroll
        for (int i = 0; i < 16; ++i) {
            const int f = i * 64 + lane;
            const int r = f >> 3, s = f & 7, q = s ^ (r & 7);
            cp16(vbat + (size_t)r * CTX + js * 64 + q * 8, Vb + bi * 16384 + i * 1024);
        }
    };
    stage(0, 0);
    for (int js = 0; js < nsteps; ++js) {
        const int cur = js & 1;
        __builtin_amdgcn_s_waitcnt(0);
        bf16x8 kfr[4][4], vfr[2][8];
        #pragma unroll
        for (int nt = 0; nt < 4; ++nt) {
            const char* rp = Kb + cur * 16384 + (nt * 16 + c) * 256;
            #pragma unroll
            for (int ks = 0; ks < 4; ++ks)
                kfr[nt][ks] = *(const bf16x8*)(rp + (((ks * 4 + p) ^ u7) * 16));
        }
        #pragma unroll
        for (int mt = 0; mt < 8; ++mt) {
            const char* rp = Vb + cur * 16384 + (mt * 16 + c) * 128;
            #pragma unroll
            for (int ch = 0; ch < 2; ++ch)
                vfr[ch][mt] = *(const bf16x8*)(rp + (((ch * 4 + p) ^ u7) * 16));
        }
        if (js + 1 < nsteps) stage(cur ^ 1, js + 1);
        const int c0 = js * 64;
        f32x4 st[4];
        #pragma unroll
        for (int nt = 0; nt < 4; ++nt) st[nt] = (f32x4){0.f, 0.f, 0.f, 0.f};
        #pragma unroll
        for (int ks = 0; ks < 4; ++ks)
            #pragma unroll
            for (int nt = 0; nt < 4; ++nt)
                st[nt] = __builtin_amdgcn_mfma_f32_16x16x32_bf16(kfr[nt][ks], qf[ks], st[nt], 0, 0, 0);
        float s[4][4];
        float lm = -FINF;
        if (js == nsteps - 1) {
            #pragma unroll
            for (int nt = 0; nt < 4; ++nt)
                #pragma unroll
                for (int r = 0; r < 4; ++r) {
                    const int kv = c0 + nt * 16 + p * 4 + r;
                    float v = st[nt][r] * scale2;
                    v = (kv <= qg) ? v : -FINF;
                    s[nt][r] = v;
                    lm = fmaxf(lm, v);
                }
        } else {
            #pragma unroll
            for (int nt = 0; nt < 4; ++nt)
                #pragma unroll
                for (int r = 0; r < 4; ++r) {
                    const float v = st[nt][r] * scale2;
                    s[nt][r] = v;
                    lm = fmaxf(lm, v);
                }
        }
        lm = fmaxf(lm, __shfl_xor(lm, 16, 64));
        lm = fmaxf(lm, __shfl_xor(lm, 32, 64));
        const float m_new = fmaxf(m, lm);
        const float alpha = fexp2(m - m_new);
        float ls = 0.f;
        #pragma unroll
        for (int nt = 0; nt < 4; ++nt)
            #pragma unroll
            for (int r = 0; r < 4; ++r) {
                const float pv = fexp2(s[nt][r] - m_new);
                s[nt][r] = pv;
                ls += pv;
            }
        ls += __shfl_xor(ls, 16, 64);
        ls += __shfl_xor(ls, 32, 64);
        l = l * alpha + ls;
        m = m_new;
        #pragma unroll
        for (int i = 0; i < 8; ++i) {
            o[i][0] *= alpha; o[i][1] *= alpha;
            o[i][2] *= alpha; o[i][3] *= alpha;
        }
        #pragma unroll
        for (int ch = 0; ch < 2; ++ch) {
            const unsigned pa0 = pk2(s[2*ch][0],     s[2*ch][1]);
            const unsigned pb0 = pk2(s[2*ch][2],     s[2*ch][3]);
            const unsigned pa1 = pk2(s[2*ch + 1][0], s[2*ch + 1][1]);
            const unsigned pb1 = pk2(s[2*ch + 1][2], s[2*ch + 1][3]);
            const unsigned u0a = __shfl((int)pa0, slA, 64), u0b = __shfl((int)pa1, slA, 64);
            const unsigned u1a = __shfl((int)pb0, slA, 64), u1b = __shfl((int)pb1, slA, 64);
            const unsigned u2a = __shfl((int)pa0, slB, 64), u2b = __shfl((int)pa1, slB, 64);
            const unsigned u3a = __shfl((int)pb0, slB, 64), u3b = __shfl((int)pb1, slB, 64);
            union { unsigned u[4]; bf16x8 v; } pf;
            pf.u[0] = thi ? u0b : u0a;
            pf.u[1] = thi ? u1b : u1a;
            pf.u[2] = thi ? u2b : u2a;
            pf.u[3] = thi ? u3b : u3a;
            #pragma unroll
            for (int mt = 0; mt < 8; ++mt)
                o[mt] = __builtin_amdgcn_mfma_f32_16x16x32_bf16(vfr[ch][mt], pf.v, o[mt], 0, 0, 0);
        }
    }
    const float linv = 1.f / l;
    float* orow = out + ((size_t)b * CTX + t0 + c) * HEAD;
    #pragma unroll
    for (int mt = 0; mt < 8; ++mt) {
        float4 ov = make_float4(o[mt][0] * linv, o[mt][1] * linv,
                                o[mt][2] * linv, o[mt][3] * linv);
        *(float4*)&orow[mt * 16 + p * 4] = ov;
    }
}

// ---------------------------------------------------------------------------
extern "C" void kernel_launch(void* const* d_in, const int* in_sizes, int n_in,
                              void* d_out, int out_size, void* d_ws, size_t ws_size,
                              hipStream_t stream) {
    const float* x  = (const float*)d_in[0];
    const float* Wq = (const float*)d_in[1];
    const float* Wk = (const float*)d_in[2];
    const float* Wv = (const float*)d_in[3];
    float* out = (float*)d_out;

    unsigned short* Wt = (unsigned short*)d_ws;                 // 3*128*1024
    unsigned short* xb = Wt + (size_t)3 * HEAD * EMB;           // 8192*1024 bf16
    unsigned short* qb = xb + (size_t)BATCH * CTX * EMB;
    unsigned short* kb = qb + (size_t)BATCH * CTX * HEAD;
    unsigned short* vt = kb + (size_t)BATCH * CTX * HEAD;
    unsigned short* pO = vt + (size_t)BATCH * CTX * HEAD;       // 4*32*8*64*128 bf16
    float* pM = (float*)(pO + (size_t)BATCH * 32 * 8 * 64 * 128);
    float* pL = pM + (size_t)BATCH * 32 * 8 * 64;

    const size_t need = (size_t)((char*)(pL + BATCH * 32 * 8 * 64) - (char*)d_ws);

    prep_kernel<<<608, 256, 0, stream>>>(x, Wq, Wk, Wv, Wt, xb);
    proj_kernel<<<dim3((BATCH * CTX) / 32, 3), 64, 0, stream>>>(xb, Wt, qb, kb, vt);
    if (ws_size >= need) {
        attn_split_kernel<<<dim3(144, 4), 256, 0, stream>>>(qb, kb, vt, pO, pM, pL);
        attn_merge_kernel<<<dim3(32, 4), 256, 0, stream>>>(pO, pM, pL, out);
    } else {
        attn_kernel<<<BATCH * (CTX / 16), 64, 0, stream>>>(qb, kb, vt, out);
    }
}